// Round 1
// baseline (270.507 us; speedup 1.0000x reference)
//
#include <hip/hip_runtime.h>

// Problem constants (from reference setup_inputs)
constexpr int B  = 8;
constexpr int C  = 256;
constexpr int HW = 128 * 128;     // 16384 pixels per plane
constexpr int K  = 64;            // selected channels

// Ranking-equivalent uncertainty:
//   u      = -s*log(s+eps), s = sigmoid(v)
//   exact:   u = s*log(1+e^-v) - eps  (second-order error <= eps^2/(2s) ~ 1e-9)
//   The -eps term is a uniform per-element shift -> uniform mean shift -> rank-invariant.
//   A positive constant factor (1/ln2) is also rank-invariant, so use log2.
//   u' = log2(1+e^-v) * rcp(1+e^-v)   -- 6 VALU ops, 3 transcendental, no IEEE divide.
__device__ __forceinline__ float uncert_rank(float v) {
    float t = __expf(-v);                    // e^-v  (v_mul + v_exp)
    float a = 1.0f + t;
    return __log2f(a) * __builtin_amdgcn_rcpf(a);
}

// Kernel 1: score[b,c] = rank-equivalent mean uncertainty over the plane.
// One block (256 threads) per (b,c) plane: 16384 floats = 4096 float4.
__global__ __launch_bounds__(256) void score_kernel(const float* __restrict__ x,
                                                    float* __restrict__ score) {
    const int plane = blockIdx.x;                       // b*C + c
    const float4* xp = (const float4*)(x + (size_t)plane * HW);
    const int t = threadIdx.x;

    float acc = 0.0f;
#pragma unroll
    for (int i = 0; i < 16; ++i) {
        float4 v = xp[t + i * 256];
        acc += uncert_rank(v.x) + uncert_rank(v.y) + uncert_rank(v.z) + uncert_rank(v.w);
    }
    // wave (64-lane) reduce
#pragma unroll
    for (int off = 32; off > 0; off >>= 1) acc += __shfl_down(acc, off, 64);

    __shared__ float smem[4];
    if ((t & 63) == 0) smem[t >> 6] = acc;
    __syncthreads();
    if (t == 0) score[plane] = smem[0] + smem[1] + smem[2] + smem[3];  // scale rank-invariant
}

// Kernel 2: per batch, exact rank of each channel by ascending score with
// lax.top_k tie-break (lower index first). sel[b][rank] = channel, rank < K.
__global__ __launch_bounds__(256) void topk_kernel(const float* __restrict__ score,
                                                   int* __restrict__ sel) {
    const int b = blockIdx.x;
    const int t = threadIdx.x;                          // channel, 0..255
    __shared__ float sc[C];
    sc[t] = score[b * C + t];
    __syncthreads();

    const float my = sc[t];
    int rank = 0;
#pragma unroll 8
    for (int j = 0; j < C; ++j) {
        float o = sc[j];
        rank += (o < my) || (o == my && j < t);
    }
    if (rank < K) sel[b * K + rank] = t;
}

// Kernel 3 (fused attn + multiply):
// Each thread owns one float2 (2 pixels) of one batch.
// Phase A: attn = sigmoid(bias + sum_k w[k]*x[b,sel[k],p])  -- kept in registers.
// Phase B: loop all 256 channels: out[b,c,p] = x[b,c,p] * attn.
// Grid = B*32 = 256 blocks (1 per CU), 256 threads (4 waves).
__global__ __launch_bounds__(256) void attn_mul_kernel(const float* __restrict__ x,
                                                       const int* __restrict__ sel,
                                                       const float* __restrict__ w,
                                                       const float* __restrict__ bias,
                                                       float* __restrict__ out) {
    const int b     = blockIdx.x >> 5;                  // 32 chunks per batch
    const int chunk = blockIdx.x & 31;
    const int t     = threadIdx.x;

    __shared__ float ws[K];
    __shared__ int   chs[K];
    if (t < K) { ws[t] = w[t]; chs[t] = sel[b * K + t]; }
    __syncthreads();

    const int p2 = chunk * 256 + t;                     // float2 idx in plane [0, 8192)
    const float2* xb = (const float2*)(x + (size_t)b * C * HW);
    float2*       ob = (float2*)(out + (size_t)b * C * HW);

    // Phase A: weighted sum over the 64 selected channels.
    float ax = 0.f, ay = 0.f;
#pragma unroll 16
    for (int k = 0; k < K; ++k) {
        float2 v = xb[(size_t)chs[k] * (HW / 2) + p2];
        float wk = ws[k];
        ax += wk * v.x; ay += wk * v.y;
    }
    const float b0 = bias[0];
    float ea = __expf(-(ax + b0));
    float eb = __expf(-(ay + b0));
    const float sa = __builtin_amdgcn_rcpf(1.0f + ea);  // sigmoid, ~1 ulp
    const float sb = __builtin_amdgcn_rcpf(1.0f + eb);

    // Phase B: stream all channels, attn stays in registers.
#pragma unroll 8
    for (int c = 0; c < C; ++c) {
        const size_t idx = (size_t)c * (HW / 2) + p2;
        float2 v = xb[idx];
        float2 o; o.x = v.x * sa; o.y = v.y * sb;
        ob[idx] = o;
    }
}

extern "C" void kernel_launch(void* const* d_in, const int* in_sizes, int n_in,
                              void* d_out, int out_size, void* d_ws, size_t ws_size,
                              hipStream_t stream) {
    const float* x    = (const float*)d_in[0];
    const float* w    = (const float*)d_in[1];
    const float* bias = (const float*)d_in[2];
    float* out = (float*)d_out;

    char* ws = (char*)d_ws;
    float* score = (float*)ws;                 // 2048 floats = 8 KiB
    int*   sel   = (int*)(ws + 8192);          // 512 ints   = 2 KiB

    score_kernel<<<B * C, 256, 0, stream>>>(x, score);
    topk_kernel<<<B, C, 0, stream>>>(score, sel);
    attn_mul_kernel<<<B * 32, 256, 0, stream>>>(x, sel, w, bias, out);
}

// Round 2
// 261.031 us; speedup vs baseline: 1.0363x; 1.0363x over previous
//
#include <hip/hip_runtime.h>

// Problem constants (from reference setup_inputs)
constexpr int B  = 8;
constexpr int C  = 256;
constexpr int HW = 128 * 128;     // 16384 pixels per plane
constexpr int K  = 64;            // selected channels

// Ranking-equivalent uncertainty:
//   u = -s*log(s+eps), s = sigmoid(v)
//   exact: u = s*log(1+e^-v) - eps  (the -eps is a uniform shift -> rank-invariant;
//   positive constant factor 1/ln2 also rank-invariant, so use log2)
//   u' = log2(1+e^-v) * rcp(1+e^-v)
__device__ __forceinline__ float uncert_rank(float v) {
    float t = __expf(-v);
    float a = 1.0f + t;
    return __log2f(a) * __builtin_amdgcn_rcpf(a);
}

// Kernel 1: score[b,c] = rank-equivalent mean uncertainty over the plane.
// One block (256 threads) per (b,c) plane: 16384 floats = 4096 float4. BW-bound (~80 us).
__global__ __launch_bounds__(256) void score_kernel(const float* __restrict__ x,
                                                    float* __restrict__ score) {
    const int plane = blockIdx.x;                       // b*C + c
    const float4* xp = (const float4*)(x + (size_t)plane * HW);
    const int t = threadIdx.x;

    float acc = 0.0f;
#pragma unroll
    for (int i = 0; i < 16; ++i) {
        float4 v = xp[t + i * 256];
        acc += uncert_rank(v.x) + uncert_rank(v.y) + uncert_rank(v.z) + uncert_rank(v.w);
    }
#pragma unroll
    for (int off = 32; off > 0; off >>= 1) acc += __shfl_down(acc, off, 64);

    __shared__ float smem[4];
    if ((t & 63) == 0) smem[t >> 6] = acc;
    __syncthreads();
    if (t == 0) score[plane] = smem[0] + smem[1] + smem[2] + smem[3];  // scale rank-invariant
}

// Kernel 2 (fused topk + attn + multiply), traffic = exactly 1 read of x + 1 write of out:
//  - every block redundantly ranks the 256 channel scores (deterministic, ~1 us)
//  - Phase A: read the 64 selected channels once; STASH values in 128 VGPRs while
//    accumulating the weighted sum; attn = sigmoid(sum + bias) stays in registers
//  - Phase A': write selected-channel outputs from the stash (no re-read)
//  - Phase B: stream the 192 unselected channels: out = x * attn
// Grid = B*32 = 256 blocks (1/CU, 4 waves/CU), 256 threads, one float2 (2 px) per thread.
// VGPR stash costs no occupancy at 1 block/CU; loops fully unrolled so stash
// indices are compile-time constants (runtime-indexed arrays would spill to scratch).
__global__ __launch_bounds__(256, 1) void attn_mul_kernel(const float* __restrict__ x,
                                                          const float* __restrict__ score,
                                                          const float* __restrict__ w,
                                                          const float* __restrict__ bias,
                                                          float* __restrict__ out) {
    const int b     = blockIdx.x >> 5;                  // 32 chunks per batch
    const int chunk = blockIdx.x & 31;
    const int t     = threadIdx.x;                      // also = channel for ranking

    __shared__ float sc[C];
    __shared__ float ws[K];
    __shared__ int   chs[K];                            // selected channel per rank
    __shared__ int   unch[C - K];                       // unselected channels

    sc[t] = score[b * C + t];
    if (t < K) ws[t] = w[t];
    __syncthreads();

    {   // exact rank with lax.top_k tie-break (lower index first)
        const float my = sc[t];
        int rank = 0;
#pragma unroll 8
        for (int j = 0; j < C; ++j) {
            float o = sc[j];
            rank += (o < my) || (o == my && j < t);
        }
        if (rank < K) chs[rank] = t;
        else          unch[rank - K] = t;
    }
    __syncthreads();

    const int p2 = chunk * 256 + t;                     // float2 idx in plane [0, 8192)
    const float2* xb = (const float2*)(x + (size_t)b * C * HW);
    float2*       ob = (float2*)(out + (size_t)b * C * HW);

    // Phase A: weighted sum over the 64 selected channels, stashing values.
    float2 st[K];
    float ax = 0.f, ay = 0.f;
#pragma unroll
    for (int k = 0; k < K; ++k) {
        float2 v = xb[(size_t)chs[k] * (HW / 2) + p2];
        st[k] = v;
        float wk = ws[k];
        ax += wk * v.x; ay += wk * v.y;
    }
    const float b0 = bias[0];
    const float sa = __builtin_amdgcn_rcpf(1.0f + __expf(-(ax + b0)));  // sigmoid
    const float sb = __builtin_amdgcn_rcpf(1.0f + __expf(-(ay + b0)));

    // Phase A': selected-channel outputs from the stash — no re-read of x.
#pragma unroll
    for (int k = 0; k < K; ++k) {
        float2 o; o.x = st[k].x * sa; o.y = st[k].y * sb;
        ob[(size_t)chs[k] * (HW / 2) + p2] = o;
    }

    // Phase B: stream the 192 unselected channels.
#pragma unroll 8
    for (int j = 0; j < C - K; ++j) {
        const size_t idx = (size_t)unch[j] * (HW / 2) + p2;
        float2 v = xb[idx];
        float2 o; o.x = v.x * sa; o.y = v.y * sb;
        ob[idx] = o;
    }
}

extern "C" void kernel_launch(void* const* d_in, const int* in_sizes, int n_in,
                              void* d_out, int out_size, void* d_ws, size_t ws_size,
                              hipStream_t stream) {
    const float* x    = (const float*)d_in[0];
    const float* w    = (const float*)d_in[1];
    const float* bias = (const float*)d_in[2];
    float* out = (float*)d_out;

    float* score = (float*)d_ws;               // 2048 floats = 8 KiB

    score_kernel<<<B * C, 256, 0, stream>>>(x, score);
    attn_mul_kernel<<<B * 32, 256, 0, stream>>>(x, score, w, bias, out);
}

// Round 3
// 259.150 us; speedup vs baseline: 1.0438x; 1.0073x over previous
//
#include <hip/hip_runtime.h>

// Problem constants (from reference setup_inputs)
constexpr int B  = 8;
constexpr int C  = 256;
constexpr int HW = 128 * 128;     // 16384 pixels per plane
constexpr int K  = 64;            // selected channels

// Ranking-equivalent uncertainty:
//   u = -s*log(s+eps), s = sigmoid(v)
//   exact: u = s*log(1+e^-v) - eps  (the -eps is a uniform shift -> rank-invariant;
//   positive constant factor 1/ln2 also rank-invariant, so use log2)
//   u' = log2(1+e^-v) * rcp(1+e^-v)
__device__ __forceinline__ float uncert_rank(float v) {
    float t = __expf(-v);
    float a = 1.0f + t;
    return __log2f(a) * __builtin_amdgcn_rcpf(a);
}

// Kernel 1: score[b,c] = rank-equivalent mean uncertainty over the plane.
// One block (256 threads) per (b,c) plane. BW-bound (~21 us for 134 MB).
// Normal (caching) loads on purpose: this pass pulls x into L3 for kernel 2.
__global__ __launch_bounds__(256) void score_kernel(const float* __restrict__ x,
                                                    float* __restrict__ score) {
    const int plane = blockIdx.x;                       // b*C + c
    const float4* xp = (const float4*)(x + (size_t)plane * HW);
    const int t = threadIdx.x;

    float acc = 0.0f;
#pragma unroll
    for (int i = 0; i < 16; ++i) {
        float4 v = xp[t + i * 256];
        acc += uncert_rank(v.x) + uncert_rank(v.y) + uncert_rank(v.z) + uncert_rank(v.w);
    }
#pragma unroll
    for (int off = 32; off > 0; off >>= 1) acc += __shfl_down(acc, off, 64);

    __shared__ float smem[4];
    if ((t & 63) == 0) smem[t >> 6] = acc;
    __syncthreads();
    if (t == 0) score[plane] = smem[0] + smem[1] + smem[2] + smem[3];  // scale rank-invariant
}

// Kernel 2 (fused topk + attn + multiply):
//  - every block redundantly ranks the 256 channel scores (deterministic, LDS, ~us)
//  - Phase A: read the 64 selected channels once; STASH in 64 VGPRs while
//    accumulating the weighted sum; attn = sigmoid(sum + bias) stays in a register
//  - Phase A': selected-channel outputs written from the stash (no re-read)
//  - Phase B: stream the 192 unselected channels
// All x reads are normal loads -> served by L3 (x = 134 MB < 256 MiB, just loaded
// by score_kernel). All out writes are NONTEMPORAL so they don't evict x from L3.
// Grid = B*64 = 512 blocks (2/CU -> 8 waves/CU), 256 threads, 1 pixel per thread.
// __launch_bounds__(256,2) caps VGPR at 256; stash(64)+misc ~= 110, no spill.
__global__ __launch_bounds__(256, 2) void attn_mul_kernel(const float* __restrict__ x,
                                                          const float* __restrict__ score,
                                                          const float* __restrict__ w,
                                                          const float* __restrict__ bias,
                                                          float* __restrict__ out) {
    const int b     = blockIdx.x >> 6;                  // 64 chunks per batch
    const int chunk = blockIdx.x & 63;                  // 256 pixels each
    const int t     = threadIdx.x;                      // also = channel for ranking

    __shared__ float sc[C];
    __shared__ float ws[K];
    __shared__ int   chs[K];                            // selected channel per rank
    __shared__ int   unch[C - K];                       // unselected channels

    sc[t] = score[b * C + t];
    if (t < K) ws[t] = w[t];
    __syncthreads();

    {   // exact rank with lax.top_k tie-break (lower index first)
        const float my = sc[t];
        int rank = 0;
#pragma unroll 8
        for (int j = 0; j < C; ++j) {
            float o = sc[j];
            rank += (o < my) || (o == my && j < t);
        }
        if (rank < K) chs[rank] = t;
        else          unch[rank - K] = t;
    }
    __syncthreads();

    const int p = chunk * 256 + t;                      // pixel index in plane [0, 16384)
    const float* xb = x + (size_t)b * C * HW;
    float*       ob = out + (size_t)b * C * HW;

    // Phase A: weighted sum over the 64 selected channels, stashing values.
    float st[K];
    float a = 0.f;
#pragma unroll
    for (int k = 0; k < K; ++k) {
        float v = xb[(size_t)chs[k] * HW + p];
        st[k] = v;
        a += ws[k] * v;
    }
    const float sg = __builtin_amdgcn_rcpf(1.0f + __expf(-(a + bias[0])));  // sigmoid

    // Phase A': selected-channel outputs from the stash — no re-read of x.
#pragma unroll
    for (int k = 0; k < K; ++k) {
        __builtin_nontemporal_store(st[k] * sg, &ob[(size_t)chs[k] * HW + p]);
    }

    // Phase B: stream the 192 unselected channels (L3-hit reads, NT writes).
#pragma unroll 8
    for (int j = 0; j < C - K; ++j) {
        const size_t idx = (size_t)unch[j] * HW + p;
        __builtin_nontemporal_store(xb[idx] * sg, &ob[idx]);
    }
}

extern "C" void kernel_launch(void* const* d_in, const int* in_sizes, int n_in,
                              void* d_out, int out_size, void* d_ws, size_t ws_size,
                              hipStream_t stream) {
    const float* x    = (const float*)d_in[0];
    const float* w    = (const float*)d_in[1];
    const float* bias = (const float*)d_in[2];
    float* out = (float*)d_out;

    float* score = (float*)d_ws;               // 2048 floats = 8 KiB

    score_kernel<<<B * C, 256, 0, stream>>>(x, score);
    attn_mul_kernel<<<B * 64, 256, 0, stream>>>(x, score, w, bias, out);
}